// Round 5
// baseline (148.493 us; speedup 1.0000x reference)
//
#include <hip/hip_runtime.h>
#include <hip/hip_bf16.h>
#include <cmath>

typedef __bf16 bf16_t;
typedef __attribute__((ext_vector_type(4)))  __bf16 bf16x4;
typedef __attribute__((ext_vector_type(8)))  __bf16 bf16x8;
typedef __attribute__((ext_vector_type(16))) float  f32x16;
typedef __attribute__((ext_vector_type(4)))  float  f32x4;

#define HW    65536
#define BNC   8            // B * NUM_CHANS
#define CH    128          // gram chunks per bnc   (chunk = 512 px)
#define APB   64           // apply pixel-blocks per bnc (block = 1024 px)
#define GSTR  1056         // per-bnc global accum: 1024 G + 32 Sx
#define FN    65536.0f
#define REPS  1e-12f

__device__ __forceinline__ bf16_t tob(float x){ return (bf16_t)x; }

// ---------------- Kernel A: channel-gram G (32x32) + channel sums -> global atomic accum ----
// Tile 32ch x 512px staged to LDS (coalesced 1KiB global reads), rows padded to
// 1040B (65 x 16B, odd) so the 32-row ds_read_b128 fragment fetch is conflict-free.
// A and B fragments are the SAME data -> correct for any hardware k-permutation.
// Block-level partials are folded straight into Gg[bnc] with device-scope f32 atomics.
__global__ __launch_bounds__(256) void k_gram(const float* __restrict__ x,
                                              float* __restrict__ Gg)
{
    __shared__ float smemf[8320];               // 33280 B, overlaid: bf16 tile | red
    __shared__ float sxl[32];
    bf16_t (*tile)[520] = (bf16_t (*)[520])smemf;
    float  (*red)[1024] = (float  (*)[1024])smemf;

    const int bid   = blockIdx.x;
    const int bnc   = bid >> 7;
    const int chunk = bid & (CH - 1);
    const int tid   = threadIdx.x;
    const int lane  = tid & 63;
    const int wv    = tid >> 6;
    const int ch    = lane & 31;
    const int hi    = lane >> 5;

    if (tid < 32) sxl[tid] = 0.0f;
    __syncthreads();

    // ---- stage: coalesced f32x4 loads (64 lanes x 16B = 1KiB contiguous) ----
    const float* xb = x + (size_t)bnc * 32 * HW + chunk * 512;
    #pragma unroll
    for (int it = 0; it < 16; ++it) {
        int i   = tid + 256 * it;
        int row = i >> 7;                 // 128 f32x4 per 512-px row
        int c4  = i & 127;
        f32x4 v = *(const f32x4*)(xb + (size_t)row * HW + c4 * 4);
        bf16x4 b;
        b[0] = tob(v.x); b[1] = tob(v.y); b[2] = tob(v.z); b[3] = tob(v.w);
        *(bf16x4*)&tile[row][c4 * 4] = b;
    }
    __syncthreads();

    // ---- channel sums from the staged tile ----
    {
        int sch = tid >> 3, seg = tid & 7;
        float s = 0.0f;
        #pragma unroll
        for (int k8 = 0; k8 < 8; ++k8) {
            bf16x8 u = *(const bf16x8*)&tile[sch][seg * 64 + k8 * 8];
            #pragma unroll
            for (int j = 0; j < 8; ++j) s += (float)u[j];
        }
        atomicAdd(&sxl[sch], s);
    }

    // ---- MFMA: G += X X^T over this wave's 128-px window ----
    f32x16 acc;
    #pragma unroll
    for (int r = 0; r < 16; ++r) acc[r] = 0.0f;
    #pragma unroll
    for (int s8 = 0; s8 < 8; ++s8) {
        int px = wv * 128 + s8 * 16 + 8 * hi;
        bf16x8 f = *(const bf16x8*)&tile[ch][px];      // conflict-free b128
        acc = __builtin_amdgcn_mfma_f32_32x32x16_bf16(f, f, acc, 0, 0, 0);
    }
    __syncthreads();                                   // tile reads done

    // ---- cross-wave reduce via LDS overlay, fold into global accumulator ----
    #pragma unroll
    for (int r = 0; r < 16; ++r) {
        int row = (r & 3) + 8 * (r >> 2) + 4 * hi;     // verified C/D layout
        red[wv][row * 32 + ch] = acc[r];
    }
    __syncthreads();

    float* Gp = Gg + (size_t)bnc * GSTR;
    #pragma unroll
    for (int i = 0; i < 4; ++i) {
        int e = tid + 256 * i;
        atomicAdd(&Gp[e], red[0][e] + red[1][e] + red[2][e] + red[3][e]);
    }
    if (tid < 32) atomicAdd(&Gp[1024 + tid], sxl[tid]);
}

// ---------------- Kernel B: attention algebra on the 32x32 gram, emit MT, K0 ----------
// out[b, nc*32+d, n] = K0[d] + sum_e MT[e][d] * x[b, nc*32+e, n]
__global__ __launch_bounds__(1024) void k_attn(const float* __restrict__ Gg,
                                               const float* __restrict__ w_qkv,
                                               const float* __restrict__ b_qkv,
                                               const float* __restrict__ w_fus,
                                               const float* __restrict__ b_fus,
                                               const float* __restrict__ tin,
                                               float* __restrict__ MT,
                                               float* __restrict__ K0)
{
    const int bnc = blockIdx.x;          // 8 blocks
    const int nc  = bnc & 3;
    const int tid = threadIdx.x;

    __shared__ float G[1024];
    __shared__ float Sx[32];

    G[tid] = Gg[(size_t)bnc * GSTR + tid];
    if (tid < 32) Sx[tid] = Gg[(size_t)bnc * GSTR + 1024 + tid];
    __syncthreads();

    const int d = tid >> 5, j = tid & 31;
    const int cd = nc * 32 + d, cj = nc * 32 + j;
    const float Gdj = G[d * 32 + j], Gdd = G[d * 33], Gjj = G[j * 33];
    const float Sxd = Sx[d], Sxj = Sx[j];

    float mloc = 0.0f, kloc = 0.0f;
    #pragma unroll
    for (int e = 0; e < 2; ++e) {
        float aq = w_qkv[cd * 6 + e],     cq = b_qkv[cd * 6 + e];
        float ak = w_qkv[cj * 6 + 2 + e], ck = b_qkv[cj * 6 + 2 + e];
        float av = w_qkv[cj * 6 + 4 + e], cv = b_qkv[cj * 6 + 4 + e];
        float wf = w_fus[cd * 2 + e];
        float tv = tin[e * 4 + nc];

        float S  = aq * ak * Gdj + aq * ck * Sxd + cq * ak * Sxj + cq * ck * FN;
        float Nq = aq * aq * Gdd + 2.0f * aq * cq * Sxd + cq * cq * FN;
        float Nk = ak * ak * Gjj + 2.0f * ak * ck * Sxj + ck * ck * FN;
        float pre = S / (fmaxf(sqrtf(Nq), REPS) * fmaxf(sqrtf(Nk), REPS)) * tv;

        float mx = pre;
        #pragma unroll
        for (int o = 16; o; o >>= 1) mx = fmaxf(mx, __shfl_xor(mx, o));
        float p = expf(pre - mx);
        float sm = p;
        #pragma unroll
        for (int o = 16; o; o >>= 1) sm += __shfl_xor(sm, o);
        float A = p / sm;

        mloc += wf * A * av;
        kloc += wf * A * cv;
    }
    MT[bnc * 1024 + j * 32 + d] = mloc;                 // transposed for k_apply
    float kr = kloc;
    #pragma unroll
    for (int o = 16; o; o >>= 1) kr += __shfl_xor(kr, o);
    if (j == 0) K0[bnc * 32 + d] = b_fus[cd] + kr;
}

// ---------------- Kernel C: out = M * x + K0, pure-VALU, float4 pixels, 2-way d-split -----
// Each thread owns 4 consecutive pixels and 16 output channels: coalesced 1KiB loads
// AND stores; M via wave-uniform s_loads; nontemporal stores keep x resident in L2/L3.
__global__ __launch_bounds__(256) void k_apply(const float* __restrict__ x,
                                               const float* __restrict__ MT,
                                               const float* __restrict__ K0,
                                               float* __restrict__ out)
{
    const int sub = blockIdx.x & 1;           // which 16-channel half
    const int blk = (blockIdx.x >> 1) & (APB - 1);
    const int bnc = blockIdx.x >> 7;          // / (APB*2)
    const int p   = blk * 1024 + threadIdx.x * 4;

    const float* xb = x   + (size_t)bnc * 32 * HW + p;
    float*       ob = out + (size_t)bnc * 32 * HW + (size_t)sub * 16 * HW + p;
    const float* Mb = MT  + bnc * 1024 + sub * 16;  // MT[e][d], wave-uniform -> s_load
    const float* Kb = K0  + bnc * 32 + sub * 16;

    f32x4 acc[16];
    const f32x4 zz = {0.0f, 0.0f, 0.0f, 0.0f};
    #pragma unroll
    for (int dd = 0; dd < 16; ++dd) acc[dd] = zz;

    #pragma unroll 4
    for (int e = 0; e < 32; ++e) {
        f32x4 xv = *(const f32x4*)(xb + (size_t)e * HW);
        #pragma unroll
        for (int dd = 0; dd < 16; ++dd) {
            acc[dd] += xv * Mb[e * 32 + dd];
        }
    }

    #pragma unroll
    for (int dd = 0; dd < 16; ++dd) {
        f32x4 r = acc[dd] + Kb[dd];
        __builtin_nontemporal_store(r, (f32x4*)(ob + (size_t)dd * HW));
    }
}

// -------------------------------------------------------------------------------------------
extern "C" void kernel_launch(void* const* d_in, const int* in_sizes, int n_in,
                              void* d_out, int out_size, void* d_ws, size_t ws_size,
                              hipStream_t stream)
{
    (void)in_sizes; (void)n_in; (void)out_size;
    const float* x      = (const float*)d_in[0];
    const float* w_qkv  = (const float*)d_in[1];
    const float* b_qkv  = (const float*)d_in[2];
    const float* w_fus  = (const float*)d_in[3];
    const float* b_fus  = (const float*)d_in[4];
    const float* tin    = (const float*)d_in[5];
    float* out = (float*)d_out;

    // ws layout: [MT (8*1024)][K0 (8*32)][Gg (8*1056)]  = 67.7 KB total
    const size_t need = (size_t)(BNC * 1024 + BNC * 32 + BNC * GSTR) * sizeof(float);
    float* Mbuf, *K0buf, *Gg;
    if (ws_size >= need) {
        Mbuf  = (float*)d_ws;
    } else {
        // fall back: carve scratch out of d_out; k_apply fully overwrites it afterwards.
        Mbuf  = out;
    }
    K0buf = Mbuf + BNC * 1024;
    Gg    = K0buf + BNC * 32;

    hipMemsetAsync(Gg, 0, (size_t)BNC * GSTR * sizeof(float), stream);
    k_gram <<<BNC * CH,      256,  0, stream>>>(x, Gg);
    k_attn <<<BNC,           1024, 0, stream>>>(Gg, w_qkv, b_qkv, w_fus, b_fus, tin,
                                                Mbuf, K0buf);
    k_apply<<<BNC * APB * 2, 256,  0, stream>>>(x, Mbuf, K0buf, out);
}

// Round 6
// 138.147 us; speedup vs baseline: 1.0749x; 1.0749x over previous
//
#include <hip/hip_runtime.h>
#include <hip/hip_bf16.h>
#include <cmath>

typedef __bf16 bf16_t;
typedef __attribute__((ext_vector_type(4)))  __bf16 bf16x4;
typedef __attribute__((ext_vector_type(8)))  __bf16 bf16x8;
typedef __attribute__((ext_vector_type(16))) float  f32x16;
typedef __attribute__((ext_vector_type(4)))  float  f32x4;

#define HW    65536
#define BNC   8            // B * NUM_CHANS
#define CH    128          // gram chunks per bnc   (chunk = 512 px)
#define APB   64           // apply pixel-blocks per bnc (block = 1024 px)
#define GSTR  1056         // per-bnc global accum: 1024 G + 32 Sx
#define FN    65536.0f
#define REPS  1e-12f

__device__ __forceinline__ bf16_t tob(float x){ return (bf16_t)x; }

// ---------------- Kernel A: channel-gram G (32x32) + channel sums -> global atomic accum ----
// Tile 32ch x 512px staged to LDS (coalesced 1KiB global reads), rows padded to
// 1040B (65 x 16B, odd) so the 32-row ds_read_b128 fragment fetch is conflict-free.
// A and B fragments are the SAME data -> correct for any hardware k-permutation.
// Block-level partials fold straight into Gg[bnc] with device-scope f32 atomics.
__global__ __launch_bounds__(256) void k_gram(const float* __restrict__ x,
                                              float* __restrict__ Gg)
{
    __shared__ float smemf[8320];               // 33280 B, overlaid: bf16 tile | red
    __shared__ float sxl[32];
    bf16_t (*tile)[520] = (bf16_t (*)[520])smemf;
    float  (*red)[1024] = (float  (*)[1024])smemf;

    const int bid   = blockIdx.x;
    const int bnc   = bid >> 7;
    const int chunk = bid & (CH - 1);
    const int tid   = threadIdx.x;
    const int lane  = tid & 63;
    const int wv    = tid >> 6;
    const int ch    = lane & 31;
    const int hi    = lane >> 5;

    if (tid < 32) sxl[tid] = 0.0f;
    __syncthreads();

    // ---- stage: coalesced f32x4 loads (64 lanes x 16B = 1KiB contiguous) ----
    const float* xb = x + (size_t)bnc * 32 * HW + chunk * 512;
    #pragma unroll
    for (int it = 0; it < 16; ++it) {
        int i   = tid + 256 * it;
        int row = i >> 7;                 // 128 f32x4 per 512-px row
        int c4  = i & 127;
        f32x4 v = *(const f32x4*)(xb + (size_t)row * HW + c4 * 4);
        bf16x4 b;
        b[0] = tob(v.x); b[1] = tob(v.y); b[2] = tob(v.z); b[3] = tob(v.w);
        *(bf16x4*)&tile[row][c4 * 4] = b;
    }
    __syncthreads();

    // ---- channel sums from the staged tile ----
    {
        int sch = tid >> 3, seg = tid & 7;
        float s = 0.0f;
        #pragma unroll
        for (int k8 = 0; k8 < 8; ++k8) {
            bf16x8 u = *(const bf16x8*)&tile[sch][seg * 64 + k8 * 8];
            #pragma unroll
            for (int j = 0; j < 8; ++j) s += (float)u[j];
        }
        atomicAdd(&sxl[sch], s);
    }

    // ---- MFMA: G += X X^T over this wave's 128-px window ----
    f32x16 acc;
    #pragma unroll
    for (int r = 0; r < 16; ++r) acc[r] = 0.0f;
    #pragma unroll
    for (int s8 = 0; s8 < 8; ++s8) {
        int px = wv * 128 + s8 * 16 + 8 * hi;
        bf16x8 f = *(const bf16x8*)&tile[ch][px];      // conflict-free b128
        acc = __builtin_amdgcn_mfma_f32_32x32x16_bf16(f, f, acc, 0, 0, 0);
    }
    __syncthreads();                                   // tile reads done

    // ---- cross-wave reduce via LDS overlay, fold into global accumulator ----
    #pragma unroll
    for (int r = 0; r < 16; ++r) {
        int row = (r & 3) + 8 * (r >> 2) + 4 * hi;     // verified C/D layout
        red[wv][row * 32 + ch] = acc[r];
    }
    __syncthreads();

    float* Gp = Gg + (size_t)bnc * GSTR;
    #pragma unroll
    for (int i = 0; i < 4; ++i) {
        int e = tid + 256 * i;
        atomicAdd(&Gp[e], red[0][e] + red[1][e] + red[2][e] + red[3][e]);
    }
    if (tid < 32) atomicAdd(&Gp[1024 + tid], sxl[tid]);
}

// ---------------- Kernel B: attention algebra on the 32x32 gram, emit MT, K0 ----------
// out[b, nc*32+d, n] = K0[d] + sum_e MT[e][d] * x[b, nc*32+e, n]
__global__ __launch_bounds__(1024) void k_attn(const float* __restrict__ Gg,
                                               const float* __restrict__ w_qkv,
                                               const float* __restrict__ b_qkv,
                                               const float* __restrict__ w_fus,
                                               const float* __restrict__ b_fus,
                                               const float* __restrict__ tin,
                                               float* __restrict__ MT,
                                               float* __restrict__ K0)
{
    const int bnc = blockIdx.x;          // 8 blocks
    const int nc  = bnc & 3;
    const int tid = threadIdx.x;

    __shared__ float G[1024];
    __shared__ float Sx[32];

    G[tid] = Gg[(size_t)bnc * GSTR + tid];
    if (tid < 32) Sx[tid] = Gg[(size_t)bnc * GSTR + 1024 + tid];
    __syncthreads();

    const int d = tid >> 5, j = tid & 31;
    const int cd = nc * 32 + d, cj = nc * 32 + j;
    const float Gdj = G[d * 32 + j], Gdd = G[d * 33], Gjj = G[j * 33];
    const float Sxd = Sx[d], Sxj = Sx[j];

    float mloc = 0.0f, kloc = 0.0f;
    #pragma unroll
    for (int e = 0; e < 2; ++e) {
        float aq = w_qkv[cd * 6 + e],     cq = b_qkv[cd * 6 + e];
        float ak = w_qkv[cj * 6 + 2 + e], ck = b_qkv[cj * 6 + 2 + e];
        float av = w_qkv[cj * 6 + 4 + e], cv = b_qkv[cj * 6 + 4 + e];
        float wf = w_fus[cd * 2 + e];
        float tv = tin[e * 4 + nc];

        float S  = aq * ak * Gdj + aq * ck * Sxd + cq * ak * Sxj + cq * ck * FN;
        float Nq = aq * aq * Gdd + 2.0f * aq * cq * Sxd + cq * cq * FN;
        float Nk = ak * ak * Gjj + 2.0f * ak * ck * Sxj + ck * ck * FN;
        float pre = S / (fmaxf(sqrtf(Nq), REPS) * fmaxf(sqrtf(Nk), REPS)) * tv;

        float mx = pre;
        #pragma unroll
        for (int o = 16; o; o >>= 1) mx = fmaxf(mx, __shfl_xor(mx, o));
        float p = expf(pre - mx);
        float sm = p;
        #pragma unroll
        for (int o = 16; o; o >>= 1) sm += __shfl_xor(sm, o);
        float A = p / sm;

        mloc += wf * A * av;
        kloc += wf * A * cv;
    }
    MT[bnc * 1024 + j * 32 + d] = mloc;                 // transposed for k_apply
    float kr = kloc;
    #pragma unroll
    for (int o = 16; o; o >>= 1) kr += __shfl_xor(kr, o);
    if (j == 0) K0[bnc * 32 + d] = b_fus[cd] + kr;
}

// ---------------- Kernel C: out = M * x + K0, pure-VALU, float4 pixels -------------------
// Each thread owns 4 consecutive pixels x all 32 output channels: coalesced 1KiB loads
// AND stores, x read exactly once; M via wave-uniform s_loads; nontemporal stores keep
// x resident in L2/L3 for the streaming read.
__global__ __launch_bounds__(256) void k_apply(const float* __restrict__ x,
                                               const float* __restrict__ MT,
                                               const float* __restrict__ K0,
                                               float* __restrict__ out)
{
    const int bnc = blockIdx.x >> 6;          // / APB
    const int blk = blockIdx.x & (APB - 1);
    const int p   = blk * 1024 + threadIdx.x * 4;

    const float* xb = x   + (size_t)bnc * 32 * HW + p;
    float*       ob = out + (size_t)bnc * 32 * HW + p;
    const float* Mb = MT  + bnc * 1024;       // MT[e][d], wave-uniform -> s_load
    const float* Kb = K0  + bnc * 32;

    f32x4 acc[32];
    const f32x4 zz = {0.0f, 0.0f, 0.0f, 0.0f};
    #pragma unroll
    for (int d = 0; d < 32; ++d) acc[d] = zz;

    #pragma unroll 4
    for (int e = 0; e < 32; ++e) {
        f32x4 xv = *(const f32x4*)(xb + (size_t)e * HW);
        #pragma unroll
        for (int d = 0; d < 32; ++d) {
            acc[d] += xv * Mb[e * 32 + d];
        }
    }

    #pragma unroll
    for (int d = 0; d < 32; ++d) {
        f32x4 r = acc[d] + Kb[d];
        __builtin_nontemporal_store(r, (f32x4*)(ob + (size_t)d * HW));
    }
}

// -------------------------------------------------------------------------------------------
extern "C" void kernel_launch(void* const* d_in, const int* in_sizes, int n_in,
                              void* d_out, int out_size, void* d_ws, size_t ws_size,
                              hipStream_t stream)
{
    (void)in_sizes; (void)n_in; (void)out_size;
    const float* x      = (const float*)d_in[0];
    const float* w_qkv  = (const float*)d_in[1];
    const float* b_qkv  = (const float*)d_in[2];
    const float* w_fus  = (const float*)d_in[3];
    const float* b_fus  = (const float*)d_in[4];
    const float* tin    = (const float*)d_in[5];
    float* out = (float*)d_out;

    // ws layout: [MT (8*1024)][K0 (8*32)][Gg (8*1056)]  = 67.7 KB total
    const size_t need = (size_t)(BNC * 1024 + BNC * 32 + BNC * GSTR) * sizeof(float);
    float* Mbuf, *K0buf, *Gg;
    if (ws_size >= need) {
        Mbuf  = (float*)d_ws;
    } else {
        // fall back: carve scratch out of d_out; k_apply fully overwrites it afterwards.
        Mbuf  = out;
    }
    K0buf = Mbuf + BNC * 1024;
    Gg    = K0buf + BNC * 32;

    hipMemsetAsync(Gg, 0, (size_t)BNC * GSTR * sizeof(float), stream);
    k_gram <<<BNC * CH,  256,  0, stream>>>(x, Gg);
    k_attn <<<BNC,       1024, 0, stream>>>(Gg, w_qkv, b_qkv, w_fus, b_fus, tin,
                                            Mbuf, K0buf);
    k_apply<<<BNC * APB, 256,  0, stream>>>(x, Mbuf, K0buf, out);
}